// Round 4
// baseline (923.796 us; speedup 1.0000x reference)
//
#include <hip/hip_runtime.h>
#include <hip/hip_bf16.h>
#include <stdint.h>

// Bayesian MHA forward for MI355X (round 4).
// All-f16 MFMA pipeline (f32 accumulate).
// Attn: K double-buffered LDS, V/Vv single-buffered (latency hidden under
// scores/softmax), x/x2 double-buffered. 52.5KB LDS -> 3 blocks/CU.

#define D_MODEL 1024
#define NSEQ    1024
#define BATCH   8
#define NHEADS  16
#define DK      64
#define TOK     8192   // BATCH*NSEQ

typedef _Float16  h8  __attribute__((ext_vector_type(8)));
typedef float     f4  __attribute__((ext_vector_type(4)));

__device__ __forceinline__ f4 mfma_h(h8 a, h8 b, f4 c){
  return __builtin_amdgcn_mfma_f32_16x16x32_f16(a, b, c, 0, 0, 0);
}

// global -> LDS async copy, 16B per lane. LDS dest must be (uniform base + lane*16).
__device__ __forceinline__ void async_copy16(void* lds, const void* g){
  __builtin_amdgcn_global_load_lds(
      (const __attribute__((address_space(1))) unsigned int*)(uintptr_t)g,
      (__attribute__((address_space(3))) unsigned int*)(unsigned int)(uintptr_t)lds,
      16, 0, 0);
}

__device__ __forceinline__ float softplusf(float x){
  return (x > 20.f) ? x : log1pf(__expf(x));
}

// ---------------- prep kernels ----------------

// Hh = f16(H), H2h = f16(H*H)
__global__ __launch_bounds__(256) void prep_H(
    const float* __restrict__ in, _Float16* __restrict__ o, _Float16* __restrict__ sq, int n){
  int i = (blockIdx.x*256 + threadIdx.x)*4;
  if (i >= n) return;
  float4 v = *(const float4*)(in + i);
  float vv[4] = {v.x, v.y, v.z, v.w};
  #pragma unroll
  for (int j=0;j<4;j++){
    o[i+j]  = (_Float16)vv[j];
    sq[i+j] = (_Float16)(vv[j]*vv[j]);
  }
}

__global__ __launch_bounds__(256) void cast_f16(
    const float* __restrict__ in, _Float16* __restrict__ out, int n){
  int i = (blockIdx.x*256 + threadIdx.x)*4;
  if (i >= n) return;
  float4 v = *(const float4*)(in + i);
  out[i+0] = (_Float16)v.x; out[i+1] = (_Float16)v.y;
  out[i+2] = (_Float16)v.z; out[i+3] = (_Float16)v.w;
}

// out = f16(softplus(x)^2)
__global__ __launch_bounds__(256) void sp2_f16(
    const float* __restrict__ in, _Float16* __restrict__ out, int n){
  int i = (blockIdx.x*256 + threadIdx.x)*4;
  if (i >= n) return;
  float4 v = *(const float4*)(in + i);
  float vv[4] = {v.x, v.y, v.z, v.w};
  #pragma unroll
  for (int j=0;j<4;j++){ float s = softplusf(vv[j]); out[i+j] = (_Float16)(s*s); }
}

// xh = f16(x_raw), x2[t] = sum_j x[t][j]^2
__global__ __launch_bounds__(256) void prep_x(
    const float* __restrict__ x, _Float16* __restrict__ xh, float* __restrict__ x2, int T){
  int t = blockIdx.x*256 + threadIdx.x;
  if (t >= T) return;
  const float* p = x + (size_t)t*16;
  float s = 0.f;
  #pragma unroll
  for (int j=0;j<16;j++){
    float f = p[j];
    xh[(size_t)t*16 + j] = (_Float16)f;
    s += f*f;
  }
  x2[t] = s;
}

// ---------------- fused GEMM: C = A @ Wcat^T (+bias) ----------------
// MODE 0: projections. 4 segments of 1024 cols: Q, K, V, Vv.
//   A = Hh (segs 0-2) or H2h (seg 3). Outputs: Qh/Kh [row][col] f16,
//   Vt/Vvt transposed [b][col][row&1023] f16.
// MODE 1: outputs. 2 segments: out_mean (f32), out_var (f32, += addend in place).
// 128x128 tile, BK=32, 4 waves (2x2). XOR-swizzled LDS chunks. XCD block swizzle.
template<int MODE>
__global__ __launch_bounds__(256) void gemm_fused(
    const _Float16* __restrict__ A0, const _Float16* __restrict__ A1,
    const _Float16* __restrict__ Wcat,
    const float* __restrict__ bias0, const float* __restrict__ bias1,
    const float* __restrict__ bias2, const float* __restrict__ bias3,
    _Float16* __restrict__ Qo, _Float16* __restrict__ Ko,
    _Float16* __restrict__ Vto, _Float16* __restrict__ Vvto,
    float* __restrict__ meanO, float* __restrict__ varO)
{
  constexpr int NBN = (MODE==0) ? 32 : 16;     // n-tiles (4096 or 2048 cols)
  __shared__ _Float16 sA[128*32];
  __shared__ _Float16 sB[128*32];
  const int tid = threadIdx.x;
  const int lane = tid & 63;
  const int wid  = tid >> 6;
  const int wm = wid >> 1, wn = wid & 1;
  const int l15 = lane & 15, l4 = lane >> 4;
  const int nwg = 64*NBN;
  const int bid = blockIdx.x;
  const int swz = (bid & 7) * (nwg >> 3) + (bid >> 3);
  const int bm = swz / NBN, bn = swz % NBN;
  const int row0 = bm << 7, col0 = bn << 7;
  const int seg = col0 >> 10;

  const _Float16* A = (MODE==0) ? (seg < 3 ? A0 : A1) : (seg == 0 ? A0 : A1);
  const _Float16* B = Wcat + (size_t)col0 * 1024;

  f4 acc[4][4];
  #pragma unroll
  for (int i=0;i<4;i++)
    #pragma unroll
    for (int j=0;j<4;j++)
      #pragma unroll
      for (int r=0;r<4;r++) acc[i][j][r] = 0.f;

  const int c0 = tid, c1 = tid + 256;
  const int r0 = c0 >> 2, ch0 = c0 & 3;
  const int r1 = c1 >> 2, ch1 = c1 & 3;
  const int k0off = ((ch0 ^ (r0 & 3)) << 3);
  const int k1off = ((ch1 ^ (r1 & 3)) << 3);

  for (int kt = 0; kt < 1024; kt += 32){
    __syncthreads();
    async_copy16(&sA[c0*8], A + (size_t)(row0+r0)*1024 + kt + k0off);
    async_copy16(&sA[c1*8], A + (size_t)(row0+r1)*1024 + kt + k1off);
    async_copy16(&sB[c0*8], B + (size_t)r0*1024 + kt + k0off);
    async_copy16(&sB[c1*8], B + (size_t)r1*1024 + kt + k1off);
    __syncthreads();

    h8 a[4], b[4];
    #pragma unroll
    for (int mf=0; mf<4; mf++){
      int r  = (wm<<6) + (mf<<4) + l15;
      int ck = l4 ^ (r & 3);
      a[mf] = *(const h8*)&sA[r*32 + ck*8];
    }
    #pragma unroll
    for (int nf=0; nf<4; nf++){
      int r  = (wn<<6) + (nf<<4) + l15;
      int ck = l4 ^ (r & 3);
      b[nf] = *(const h8*)&sB[r*32 + ck*8];
    }
    __builtin_amdgcn_s_setprio(1);
    #pragma unroll
    for (int mf=0; mf<4; mf++)
      #pragma unroll
      for (int nf=0; nf<4; nf++)
        acc[mf][nf] = mfma_h(a[mf], b[nf], acc[mf][nf]);
    __builtin_amdgcn_s_setprio(0);
  }

  const float* bias = (MODE==0)
      ? (seg==0 ? bias0 : seg==1 ? bias1 : seg==2 ? bias2 : bias3)
      : (seg==0 ? bias0 : bias1);
  const bool sp2 = (MODE==0) ? (seg==3) : (seg==1);

  #pragma unroll
  for (int nf=0; nf<4; nf++){
    int colg = col0 + (wn<<6) + (nf<<4) + l15;
    int colm = colg & 1023;
    float bb = bias[colm];
    float bv = sp2 ? ({ float s = softplusf(bb); s*s; }) : bb;
    #pragma unroll
    for (int mf=0; mf<4; mf++){
      int rbase = row0 + (wm<<6) + (mf<<4) + (l4<<2);
      #pragma unroll
      for (int r=0;r<4;r++){
        int row = rbase + r;
        float v = acc[mf][nf][r] + bv;
        if (MODE==0){
          if (seg==0)      Qo[(size_t)row*1024 + colm] = (_Float16)v;
          else if (seg==1) Ko[(size_t)row*1024 + colm] = (_Float16)v;
          else {
            _Float16* T = (seg==2) ? Vto : Vvto;
            T[((size_t)(row>>10)<<20) + ((size_t)colm<<10) + (row & 1023)] = (_Float16)v;
          }
        } else {
          size_t idx = (size_t)row*1024 + colm;
          if (seg==0) meanO[idx] = v;
          else        varO[idx] = v + varO[idx];
        }
      }
    }
  }
}

// ---------------- fused attention (flash-style, + RBF scores) ----------------
// grid: 1024 blocks = 8 q-tiles x (B*H). 256 thr = 4 waves, each wave owns 32 q-rows.
// K/x double-buffered (prefetch overlaps scores), V/Vv single-buffered
// (staged at iter top, latency hidden under scores+softmax, consumed in PV).
__global__ __launch_bounds__(256, 3) void attn_kernel(
    const _Float16* __restrict__ Qh, const _Float16* __restrict__ Kh,
    const _Float16* __restrict__ Vt, const _Float16* __restrict__ Vvt,
    const _Float16* __restrict__ xh, const float* __restrict__ x2g,
    const float* __restrict__ log_sigma_f, const float* __restrict__ log_length,
    _Float16* __restrict__ ctx_out, _Float16* __restrict__ ctx2_out,
    float* __restrict__ var_out)
{
  // XCD swizzle: 8 qt-blocks of the same (b,h) land on the same XCD -> K/V L2 reuse
  const int bid = blockIdx.x;
  const int swz = (bid & 7) * 128 + (bid >> 3);
  const int qt = swz & 7;
  const int bh = swz >> 3;
  const int b  = bh >> 4, h = bh & 15;
  const int tid = threadIdx.x;
  const int lane = tid & 63, wid = tid >> 6;
  const int l15 = lane & 15, l4 = lane >> 4;
  const float sig2   = __expf(2.f*log_sigma_f[h]);
  const float inv2l2 = 0.5f*__expf(-2.f*log_length[h]);

  __shared__ _Float16 sK[2][4096];   // 16KB [m][d] 64x64, XOR-swizzled
  __shared__ _Float16 sV[4096];      // 8KB  [d][m]
  __shared__ _Float16 sVv[4096];     // 8KB  [d][m]
  __shared__ _Float16 sx[2][1024];   // 4KB  [m][16]
  __shared__ float    sx2[2][64];    // 512B
  __shared__ _Float16 sP[8192];      // 16KB [q][m] 128x64, swizzled, wave-private rows

  const int t0 = b*NSEQ + qt*128;
  const int wq = wid*32;

  // Q fragments (f16), held in regs for the whole block
  h8 qf[2][2];
  #pragma unroll
  for (int fq=0; fq<2; fq++)
    #pragma unroll
    for (int ks=0; ks<2; ks++){
      size_t off = (size_t)(t0 + wq + fq*16 + l15)*D_MODEL + h*DK + ks*32 + l4*8;
      qf[fq][ks] = *(const h8*)(Qh + off);
    }
  // x_raw q fragments (K=16 zero-padded to 32)
  h8 xq[2];
  #pragma unroll
  for (int fq=0; fq<2; fq++){
    #pragma unroll
    for (int j=0;j<8;j++) xq[fq][j] = (_Float16)0.f;
    if (l4 < 2){
      size_t off = (size_t)(t0 + wq + fq*16 + l15)*16 + l4*8;
      xq[fq] = *(const h8*)(xh + off);
    }
  }
  float x2q[2][4];
  #pragma unroll
  for (int fq=0; fq<2; fq++)
    #pragma unroll
    for (int r=0;r<4;r++) x2q[fq][r] = x2g[t0 + wq + fq*16 + l4*4 + r];

  h8 ones;
  #pragma unroll
  for (int j=0;j<8;j++) ones[j] = (_Float16)1.f;

  f4 mrun[2], lacc[2], ctx[2][4], var[2][4];
  #pragma unroll
  for (int fq=0; fq<2; fq++){
    #pragma unroll
    for (int r=0;r<4;r++){ mrun[fq][r] = -1e30f; lacc[fq][r] = 0.f; }
    #pragma unroll
    for (int fd=0; fd<4; fd++)
      #pragma unroll
      for (int r=0;r<4;r++){ ctx[fq][fd][r] = 0.f; var[fq][fd][r] = 0.f; }
  }

  // K staging: 512 chunks of 16B -> exactly 2 per thread
  auto stageK = [&](int bi, int mt){
    #pragma unroll
    for (int cc=0; cc<2; cc++){
      int c = tid + cc*256;
      int rg = c >> 3, sw = (((c & 7) ^ (rg & 7)) << 3);
      async_copy16(&sK[bi][c*8], Kh + (size_t)(b*NSEQ + mt + rg)*D_MODEL + h*DK + sw);
    }
  };
  // x/x2 staging: 128 + 16 chunks (threads 0..143)
  auto stageX = [&](int bi, int mt){
    int c = tid;
    if (c < 128){
      async_copy16(&sx[bi][c*8], xh + (size_t)(b*NSEQ + mt)*16 + c*8);
    } else if (c < 144){
      int cc = c - 128;
      async_copy16(&sx2[bi][cc*4], x2g + b*NSEQ + mt + cc*4);
    }
  };
  // V/Vv staging: 512 chunks each -> 4 per thread
  auto stageV = [&](int mt){
    #pragma unroll
    for (int cc=0; cc<2; cc++){
      int c = tid + cc*256;
      int rg = c >> 3, sw = (((c & 7) ^ (rg & 7)) << 3);
      size_t voff = ((size_t)b << 20) + (size_t)(h*DK + rg)*NSEQ + mt + sw;
      async_copy16(&sV[c*8],  Vt  + voff);
      async_copy16(&sVv[c*8], Vvt + voff);
    }
  };

  stageK(0, 0);
  stageX(0, 0);
  __syncthreads();

  for (int it = 0; it < NSEQ/64; it++){
    const int bi = it & 1;
    const int mt = it*64;
    stageV(mt);                      // consumed in PV below (after mid barrier)
    if (it + 1 < NSEQ/64){ stageK(bi^1, mt + 64); stageX(bi^1, mt + 64); }

    // scores: S = (QK^T)*0.125 + sig2*exp(-dist2*inv2l2)
    f4 S[2][4];
    #pragma unroll
    for (int fm=0; fm<4; fm++){
      int mrow = fm*16 + l15;
      h8 xb;
      #pragma unroll
      for (int j=0;j<8;j++) xb[j] = (_Float16)0.f;
      if (l4 < 2) xb = *(const h8*)&sx[bi][mrow*16 + l4*8];
      float x2m = sx2[bi][mrow];
      h8 kb0, kb1;
      { int ck0 = l4 ^ (mrow & 7);       kb0 = *(const h8*)&sK[bi][mrow*64 + ck0*8]; }
      { int ck1 = (4 + l4) ^ (mrow & 7); kb1 = *(const h8*)&sK[bi][mrow*64 + ck1*8]; }
      #pragma unroll
      for (int fq=0; fq<2; fq++){
        f4 s, xd;
        #pragma unroll
        for (int r=0;r<4;r++){ s[r]=0.f; xd[r]=0.f; }
        __builtin_amdgcn_s_setprio(1);
        s  = mfma_h(qf[fq][0], kb0, s);
        s  = mfma_h(qf[fq][1], kb1, s);
        xd = mfma_h(xq[fq], xb, xd);
        __builtin_amdgcn_s_setprio(0);
        #pragma unroll
        for (int r=0;r<4;r++){
          float d2 = fmaxf(x2q[fq][r] + x2m - 2.f*xd[r], 0.f);
          S[fq][fm][r] = s[r]*0.125f + sig2*__expf(-d2*inv2l2);
        }
      }
    }

    // online softmax with deferred max (thr=4; P <= e^4, P^2 <= e^8 fits f16)
    #pragma unroll
    for (int fq=0; fq<2; fq++){
      f4 tm;
      #pragma unroll
      for (int r=0;r<4;r++)
        tm[r] = fmaxf(fmaxf(S[fq][0][r], S[fq][1][r]), fmaxf(S[fq][2][r], S[fq][3][r]));
      #pragma unroll
      for (int mask=1; mask<16; mask<<=1)
        #pragma unroll
        for (int r=0;r<4;r++) tm[r] = fmaxf(tm[r], __shfl_xor(tm[r], mask));
      int nd = 0;
      #pragma unroll
      for (int r=0;r<4;r++) nd |= (tm[r] > mrun[fq][r] + 4.f) ? 1 : 0;
      if (__any(nd)){
        f4 sc;
        #pragma unroll
        for (int r=0;r<4;r++){
          float mn = fmaxf(mrun[fq][r], tm[r]);
          sc[r] = __expf(mrun[fq][r] - mn);
          mrun[fq][r] = mn;
          lacc[fq][r] *= sc[r];
        }
        #pragma unroll
        for (int fd=0; fd<4; fd++)
          #pragma unroll
          for (int r=0;r<4;r++){
            ctx[fq][fd][r] *= sc[r];
            var[fq][fd][r] *= sc[r]*sc[r];
          }
      }
      #pragma unroll
      for (int fm=0; fm<4; fm++)
        #pragma unroll
        for (int r=0;r<4;r++){
          float p = __expf(S[fq][fm][r] - mrun[fq][r]);
          int qrow = wq + fq*16 + l4*4 + r;
          int m    = fm*16 + l15;
          int ck   = (m>>3) ^ (qrow & 7);
          sP[qrow*64 + ck*8 + (m&7)] = (_Float16)p;
        }
    }

    __syncthreads();   // V/Vv landed (vmcnt drained) + visible to all waves

    // PV: ctx += P @ V, var += P^2 @ Vv, l += P @ 1 (f16 MFMA)
    #pragma unroll
    for (int ks=0; ks<2; ks++){
      h8 pa[2], pa2[2];
      #pragma unroll
      for (int fq=0; fq<2; fq++){
        int qrow = wq + fq*16 + l15;
        int ck = (ks*4 + l4) ^ (qrow & 7);
        pa[fq] = *(const h8*)&sP[qrow*64 + ck*8];
        pa2[fq] = pa[fq]*pa[fq];
        lacc[fq] = mfma_h(pa[fq], ones, lacc[fq]);
      }
      #pragma unroll
      for (int fd=0; fd<4; fd++){
        int drow = fd*16 + l15;
        int ck = (ks*4 + l4) ^ (drow & 7);
        h8 vb  = *(const h8*)&sV[drow*64 + ck*8];
        h8 vvb = *(const h8*)&sVv[drow*64 + ck*8];
        __builtin_amdgcn_s_setprio(1);
        #pragma unroll
        for (int fq=0; fq<2; fq++){
          ctx[fq][fd] = mfma_h(pa[fq],  vb,  ctx[fq][fd]);
          var[fq][fd] = mfma_h(pa2[fq], vvb, var[fq][fd]);
        }
        __builtin_amdgcn_s_setprio(0);
      }
    }
    __syncthreads();   // separate PV reads of sV/sVv from next iter's stageV
  }

  // epilogue: normalize; write ctx and ctx^2 as f16 (feeds out-projection GEMM)
  #pragma unroll
  for (int fq=0; fq<2; fq++)
    #pragma unroll
    for (int fd=0; fd<4; fd++){
      int col = h*DK + fd*16 + l15;
      #pragma unroll
      for (int r=0;r<4;r++){
        int t = t0 + wq + fq*16 + l4*4 + r;
        float linv = 1.f / lacc[fq][r];
        float c = ctx[fq][fd][r] * linv;
        size_t idx = (size_t)t*D_MODEL + col;
        ctx_out[idx]  = (_Float16)c;
        ctx2_out[idx] = (_Float16)(c*c);
        var_out[idx]  = var[fq][fd][r] * linv * linv;
      }
    }
}

// ---------------- host launch ----------------

extern "C" void kernel_launch(void* const* d_in, const int* in_sizes, int n_in,
                              void* d_out, int out_size, void* d_ws, size_t ws_size,
                              hipStream_t stream){
  (void)in_sizes; (void)n_in; (void)out_size; (void)ws_size;
  const float* H      = (const float*)d_in[0];
  const float* x_raw  = (const float*)d_in[1];
  const float* Wq_mu  = (const float*)d_in[2];
  const float* bq_mu  = (const float*)d_in[4];
  const float* Wk_mu  = (const float*)d_in[6];
  const float* bk_mu  = (const float*)d_in[8];
  const float* Wv_mu  = (const float*)d_in[10];
  const float* Wv_rho = (const float*)d_in[11];
  const float* bv_mu  = (const float*)d_in[12];
  const float* bv_rho = (const float*)d_in[13];
  const float* Wo_mu  = (const float*)d_in[14];
  const float* Wo_rho = (const float*)d_in[15];
  const float* bo_mu  = (const float*)d_in[16];
  const float* bo_rho = (const float*)d_in[17];
  const float* lsf    = (const float*)d_in[18];
  const float* lln    = (const float*)d_in[19];

  char* ws = (char*)d_ws;
  const size_t MB = 1024*1024;
  _Float16* Hh    = (_Float16*)(ws + 0*MB);     // 16MB
  _Float16* H2h   = (_Float16*)(ws + 16*MB);    // 16MB
  _Float16* Wcat  = (_Float16*)(ws + 32*MB);    // 8MB: [Wq|Wk|Wv|Wvs2] rows
  _Float16* Wocat = (_Float16*)(ws + 40*MB);    // 4MB: [Wo|Wos2] rows
  _Float16* Qh    = (_Float16*)(ws + 46*MB);    // 16MB
  _Float16* Kh    = (_Float16*)(ws + 62*MB);    // 16MB
  _Float16* Vt    = (_Float16*)(ws + 78*MB);    // 16MB, transposed [b][o][n]
  _Float16* Vvt   = (_Float16*)(ws + 94*MB);    // 16MB
  _Float16* ctxh  = (_Float16*)(ws + 110*MB);   // 16MB
  _Float16* ctx2h = (_Float16*)(ws + 126*MB);   // 16MB
  _Float16* xh    = (_Float16*)(ws + 142*MB);   // 256KB
  float*    x2    = (float*)(ws + 142*MB + 512*1024);  // 32KB

  float* out_mean = (float*)d_out;
  float* out_var  = out_mean + (size_t)TOK*D_MODEL;

  const int TD = TOK*D_MODEL;
  const int DD = D_MODEL*D_MODEL;

  // prep
  prep_H  <<<TD/1024, 256, 0, stream>>>(H, Hh, H2h, TD);
  cast_f16<<<DD/1024, 256, 0, stream>>>(Wq_mu, Wcat, DD);
  cast_f16<<<DD/1024, 256, 0, stream>>>(Wk_mu, Wcat + (size_t)DD, DD);
  cast_f16<<<DD/1024, 256, 0, stream>>>(Wv_mu, Wcat + 2*(size_t)DD, DD);
  sp2_f16 <<<DD/1024, 256, 0, stream>>>(Wv_rho, Wcat + 3*(size_t)DD, DD);
  cast_f16<<<DD/1024, 256, 0, stream>>>(Wo_mu, Wocat, DD);
  sp2_f16 <<<DD/1024, 256, 0, stream>>>(Wo_rho, Wocat + (size_t)DD, DD);
  prep_x  <<<TOK/256, 256, 0, stream>>>(x_raw, xh, x2, TOK);

  // fused projections: Q | K | V | Vv in one launch (grid 64 x 32)
  gemm_fused<0><<<2048, 256, 0, stream>>>(Hh, H2h, Wcat,
      bq_mu, bk_mu, bv_mu, bv_rho,
      Qh, Kh, Vt, Vvt, nullptr, nullptr);

  // attention (writes ctxh/ctx2h f16 and var_attn into out_var)
  attn_kernel<<<1024, 256, 0, stream>>>(Qh, Kh, Vt, Vvt, xh, x2, lsf, lln,
      ctxh, ctx2h, out_var);

  // fused output projections: out_mean | out_var (grid 64 x 16)
  gemm_fused<1><<<1024, 256, 0, stream>>>(ctxh, ctx2h, Wocat,
      bo_mu, bo_rho, nullptr, nullptr,
      nullptr, nullptr, nullptr, nullptr, out_mean, out_var);
}

// Round 5
// 388.664 us; speedup vs baseline: 2.3768x; 2.3768x over previous
//
#include <hip/hip_runtime.h>
#include <hip/hip_bf16.h>
#include <stdint.h>

// Bayesian MHA forward for MI355X (round 5).
// Consolidation: r2's proven attn loop (all-dbuf staging, ONE barrier/iter,
// lockstep blocks -> L2 reuse) + r3's fused GEMMs (no setprio) + direct
// f16 ctx/ctx^2 epilogue (line-grouped stores).

#define D_MODEL 1024
#define NSEQ    1024
#define BATCH   8
#define NHEADS  16
#define DK      64
#define TOK     8192   // BATCH*NSEQ

typedef _Float16  h8  __attribute__((ext_vector_type(8)));
typedef float     f4  __attribute__((ext_vector_type(4)));

__device__ __forceinline__ f4 mfma_h(h8 a, h8 b, f4 c){
  return __builtin_amdgcn_mfma_f32_16x16x32_f16(a, b, c, 0, 0, 0);
}

// global -> LDS async copy, 16B per lane. LDS dest must be (uniform base + lane*16).
__device__ __forceinline__ void async_copy16(void* lds, const void* g){
  __builtin_amdgcn_global_load_lds(
      (const __attribute__((address_space(1))) unsigned int*)(uintptr_t)g,
      (__attribute__((address_space(3))) unsigned int*)(unsigned int)(uintptr_t)lds,
      16, 0, 0);
}

__device__ __forceinline__ float softplusf(float x){
  return (x > 20.f) ? x : log1pf(__expf(x));
}

// ---------------- prep kernels ----------------

// Hh = f16(H), H2h = f16(H*H)
__global__ __launch_bounds__(256) void prep_H(
    const float* __restrict__ in, _Float16* __restrict__ o, _Float16* __restrict__ sq, int n){
  int i = (blockIdx.x*256 + threadIdx.x)*4;
  if (i >= n) return;
  float4 v = *(const float4*)(in + i);
  float vv[4] = {v.x, v.y, v.z, v.w};
  #pragma unroll
  for (int j=0;j<4;j++){
    o[i+j]  = (_Float16)vv[j];
    sq[i+j] = (_Float16)(vv[j]*vv[j]);
  }
}

__global__ __launch_bounds__(256) void cast_f16(
    const float* __restrict__ in, _Float16* __restrict__ out, int n){
  int i = (blockIdx.x*256 + threadIdx.x)*4;
  if (i >= n) return;
  float4 v = *(const float4*)(in + i);
  out[i+0] = (_Float16)v.x; out[i+1] = (_Float16)v.y;
  out[i+2] = (_Float16)v.z; out[i+3] = (_Float16)v.w;
}

// out = f16(softplus(x)^2)
__global__ __launch_bounds__(256) void sp2_f16(
    const float* __restrict__ in, _Float16* __restrict__ out, int n){
  int i = (blockIdx.x*256 + threadIdx.x)*4;
  if (i >= n) return;
  float4 v = *(const float4*)(in + i);
  float vv[4] = {v.x, v.y, v.z, v.w};
  #pragma unroll
  for (int j=0;j<4;j++){ float s = softplusf(vv[j]); out[i+j] = (_Float16)(s*s); }
}

// xh = f16(x_raw), x2[t] = sum_j x[t][j]^2
__global__ __launch_bounds__(256) void prep_x(
    const float* __restrict__ x, _Float16* __restrict__ xh, float* __restrict__ x2, int T){
  int t = blockIdx.x*256 + threadIdx.x;
  if (t >= T) return;
  const float* p = x + (size_t)t*16;
  float s = 0.f;
  #pragma unroll
  for (int j=0;j<16;j++){
    float f = p[j];
    xh[(size_t)t*16 + j] = (_Float16)f;
    s += f*f;
  }
  x2[t] = s;
}

// ---------------- fused GEMM: C = A @ Wcat^T (+bias) ----------------
// MODE 0: projections. 4 segments of 1024 cols: Q, K, V, Vv.
//   A = Hh (segs 0-2) or H2h (seg 3). Outputs: Qh/Kh [row][col] f16,
//   Vt/Vvt transposed [b][col][row&1023] f16.
// MODE 1: outputs. 2 segments: out_mean (f32), out_var (f32, += addend in place).
// 128x128 tile, BK=32, 4 waves (2x2). XOR-swizzled LDS chunks. XCD block swizzle.
template<int MODE>
__global__ __launch_bounds__(256) void gemm_fused(
    const _Float16* __restrict__ A0, const _Float16* __restrict__ A1,
    const _Float16* __restrict__ Wcat,
    const float* __restrict__ bias0, const float* __restrict__ bias1,
    const float* __restrict__ bias2, const float* __restrict__ bias3,
    _Float16* __restrict__ Qo, _Float16* __restrict__ Ko,
    _Float16* __restrict__ Vto, _Float16* __restrict__ Vvto,
    float* __restrict__ meanO, float* __restrict__ varO)
{
  constexpr int NBN = (MODE==0) ? 32 : 16;     // n-tiles (4096 or 2048 cols)
  __shared__ _Float16 sA[128*32];
  __shared__ _Float16 sB[128*32];
  const int tid = threadIdx.x;
  const int lane = tid & 63;
  const int wid  = tid >> 6;
  const int wm = wid >> 1, wn = wid & 1;
  const int l15 = lane & 15, l4 = lane >> 4;
  const int nwg = 64*NBN;
  const int bid = blockIdx.x;
  const int swz = (bid & 7) * (nwg >> 3) + (bid >> 3);
  const int bm = swz / NBN, bn = swz % NBN;
  const int row0 = bm << 7, col0 = bn << 7;
  const int seg = col0 >> 10;

  const _Float16* A = (MODE==0) ? (seg < 3 ? A0 : A1) : (seg == 0 ? A0 : A1);
  const _Float16* B = Wcat + (size_t)col0 * 1024;

  f4 acc[4][4];
  #pragma unroll
  for (int i=0;i<4;i++)
    #pragma unroll
    for (int j=0;j<4;j++)
      #pragma unroll
      for (int r=0;r<4;r++) acc[i][j][r] = 0.f;

  const int c0 = tid, c1 = tid + 256;
  const int r0 = c0 >> 2, ch0 = c0 & 3;
  const int r1 = c1 >> 2, ch1 = c1 & 3;
  const int k0off = ((ch0 ^ (r0 & 3)) << 3);
  const int k1off = ((ch1 ^ (r1 & 3)) << 3);

  for (int kt = 0; kt < 1024; kt += 32){
    __syncthreads();
    async_copy16(&sA[c0*8], A + (size_t)(row0+r0)*1024 + kt + k0off);
    async_copy16(&sA[c1*8], A + (size_t)(row0+r1)*1024 + kt + k1off);
    async_copy16(&sB[c0*8], B + (size_t)r0*1024 + kt + k0off);
    async_copy16(&sB[c1*8], B + (size_t)r1*1024 + kt + k1off);
    __syncthreads();

    h8 a[4], b[4];
    #pragma unroll
    for (int mf=0; mf<4; mf++){
      int r  = (wm<<6) + (mf<<4) + l15;
      int ck = l4 ^ (r & 3);
      a[mf] = *(const h8*)&sA[r*32 + ck*8];
    }
    #pragma unroll
    for (int nf=0; nf<4; nf++){
      int r  = (wn<<6) + (nf<<4) + l15;
      int ck = l4 ^ (r & 3);
      b[nf] = *(const h8*)&sB[r*32 + ck*8];
    }
    #pragma unroll
    for (int mf=0; mf<4; mf++)
      #pragma unroll
      for (int nf=0; nf<4; nf++)
        acc[mf][nf] = mfma_h(a[mf], b[nf], acc[mf][nf]);
  }

  const float* bias = (MODE==0)
      ? (seg==0 ? bias0 : seg==1 ? bias1 : seg==2 ? bias2 : bias3)
      : (seg==0 ? bias0 : bias1);
  const bool sp2 = (MODE==0) ? (seg==3) : (seg==1);

  #pragma unroll
  for (int nf=0; nf<4; nf++){
    int colg = col0 + (wn<<6) + (nf<<4) + l15;
    int colm = colg & 1023;
    float bb = bias[colm];
    float bv = sp2 ? ({ float s = softplusf(bb); s*s; }) : bb;
    #pragma unroll
    for (int mf=0; mf<4; mf++){
      int rbase = row0 + (wm<<6) + (mf<<4) + (l4<<2);
      #pragma unroll
      for (int r=0;r<4;r++){
        int row = rbase + r;
        float v = acc[mf][nf][r] + bv;
        if (MODE==0){
          if (seg==0)      Qo[(size_t)row*1024 + colm] = (_Float16)v;
          else if (seg==1) Ko[(size_t)row*1024 + colm] = (_Float16)v;
          else {
            _Float16* T = (seg==2) ? Vto : Vvto;
            T[((size_t)(row>>10)<<20) + ((size_t)colm<<10) + (row & 1023)] = (_Float16)v;
          }
        } else {
          size_t idx = (size_t)row*1024 + colm;
          if (seg==0) meanO[idx] = v;
          else        varO[idx] = v + varO[idx];
        }
      }
    }
  }
}

// ---------------- fused attention (flash-style, + RBF scores) ----------------
// r2-proven structure: 1024 blocks = 8 q-tiles x (B*H), 4 waves x 32 q-rows.
// ALL tiles double-buffered, ONE barrier per iteration -> blocks stay
// lockstep, 8 qt-blocks per (b,h) share K/V/Vv via L2 (FETCH ~33MB).
__global__ __launch_bounds__(256, 2) void attn_kernel(
    const _Float16* __restrict__ Qh, const _Float16* __restrict__ Kh,
    const _Float16* __restrict__ Vt, const _Float16* __restrict__ Vvt,
    const _Float16* __restrict__ xh, const float* __restrict__ x2g,
    const float* __restrict__ log_sigma_f, const float* __restrict__ log_length,
    _Float16* __restrict__ ctx_out, _Float16* __restrict__ ctx2_out,
    float* __restrict__ var_out)
{
  // XCD swizzle: 8 qt-blocks of the same (b,h) land on the same XCD
  const int bid = blockIdx.x;
  const int swz = (bid & 7) * 128 + (bid >> 3);
  const int qt = swz & 7;
  const int bh = swz >> 3;
  const int b  = bh >> 4, h = bh & 15;
  const int tid = threadIdx.x;
  const int lane = tid & 63, wid = tid >> 6;
  const int l15 = lane & 15, l4 = lane >> 4;
  const float sig2   = __expf(2.f*log_sigma_f[h]);
  const float inv2l2 = 0.5f*__expf(-2.f*log_length[h]);

  __shared__ _Float16 sK[2][4096];   // [m][d] 64x64, XOR-swizzled
  __shared__ _Float16 sV[2][4096];   // [d][m]
  __shared__ _Float16 sVv[2][4096];  // [d][m]
  __shared__ _Float16 sx[2][1024];   // [m][16]
  __shared__ float    sx2[2][64];
  __shared__ _Float16 sP[8192];      // [q][m] 128x64, swizzled, wave-private rows

  const int t0 = b*NSEQ + qt*128;
  const int wq = wid*32;

  // Q fragments (f16), held in regs for the whole block
  h8 qf[2][2];
  #pragma unroll
  for (int fq=0; fq<2; fq++)
    #pragma unroll
    for (int ks=0; ks<2; ks++){
      size_t off = (size_t)(t0 + wq + fq*16 + l15)*D_MODEL + h*DK + ks*32 + l4*8;
      qf[fq][ks] = *(const h8*)(Qh + off);
    }
  // x_raw q fragments (K=16 zero-padded to 32)
  h8 xq[2];
  #pragma unroll
  for (int fq=0; fq<2; fq++){
    #pragma unroll
    for (int j=0;j<8;j++) xq[fq][j] = (_Float16)0.f;
    if (l4 < 2){
      size_t off = (size_t)(t0 + wq + fq*16 + l15)*16 + l4*8;
      xq[fq] = *(const h8*)(xh + off);
    }
  }
  float x2q[2][4];
  #pragma unroll
  for (int fq=0; fq<2; fq++)
    #pragma unroll
    for (int r=0;r<4;r++) x2q[fq][r] = x2g[t0 + wq + fq*16 + l4*4 + r];

  h8 ones;
  #pragma unroll
  for (int j=0;j<8;j++) ones[j] = (_Float16)1.f;

  f4 mrun[2], lacc[2], ctx[2][4], var[2][4];
  #pragma unroll
  for (int fq=0; fq<2; fq++){
    #pragma unroll
    for (int r=0;r<4;r++){ mrun[fq][r] = -1e30f; lacc[fq][r] = 0.f; }
    #pragma unroll
    for (int fd=0; fd<4; fd++)
      #pragma unroll
      for (int r=0;r<4;r++){ ctx[fq][fd][r] = 0.f; var[fq][fd][r] = 0.f; }
  }

  // staging: 1680 chunks of 16B (K 512, V 512, Vv 512, x 128, x2 16)
  auto stage = [&](int bi, int mt){
    for (int c = tid; c < 1680; c += 256){
      if (c < 512){
        int rg = c >> 3, sw = (((c & 7) ^ (rg & 7)) << 3);
        async_copy16(&sK[bi][c*8], Kh + (size_t)(b*NSEQ + mt + rg)*D_MODEL + h*DK + sw);
      } else if (c < 1024){
        int cc = c - 512; int rg = cc >> 3, sw = (((cc & 7) ^ (rg & 7)) << 3);
        async_copy16(&sV[bi][cc*8], Vt + ((size_t)b << 20) + (size_t)(h*DK + rg)*NSEQ + mt + sw);
      } else if (c < 1536){
        int cc = c - 1024; int rg = cc >> 3, sw = (((cc & 7) ^ (rg & 7)) << 3);
        async_copy16(&sVv[bi][cc*8], Vvt + ((size_t)b << 20) + (size_t)(h*DK + rg)*NSEQ + mt + sw);
      } else if (c < 1664){
        int cc = c - 1536;
        async_copy16(&sx[bi][cc*8], xh + (size_t)(b*NSEQ + mt)*16 + cc*8);
      } else {
        int cc = c - 1664;
        async_copy16(&sx2[bi][cc*4], x2g + b*NSEQ + mt + cc*4);
      }
    }
  };

  stage(0, 0);
  __syncthreads();

  for (int it = 0; it < NSEQ/64; it++){
    const int bi = it & 1;
    const int mt = it*64;
    if (it + 1 < NSEQ/64) stage(bi^1, mt + 64);

    // scores: S = (QK^T)*0.125 + sig2*exp(-dist2*inv2l2)
    f4 S[2][4];
    #pragma unroll
    for (int fm=0; fm<4; fm++){
      int mrow = fm*16 + l15;
      h8 xb;
      #pragma unroll
      for (int j=0;j<8;j++) xb[j] = (_Float16)0.f;
      if (l4 < 2) xb = *(const h8*)&sx[bi][mrow*16 + l4*8];
      float x2m = sx2[bi][mrow];
      h8 kb0, kb1;
      { int ck0 = l4 ^ (mrow & 7);       kb0 = *(const h8*)&sK[bi][mrow*64 + ck0*8]; }
      { int ck1 = (4 + l4) ^ (mrow & 7); kb1 = *(const h8*)&sK[bi][mrow*64 + ck1*8]; }
      #pragma unroll
      for (int fq=0; fq<2; fq++){
        f4 s, xd;
        #pragma unroll
        for (int r=0;r<4;r++){ s[r]=0.f; xd[r]=0.f; }
        s  = mfma_h(qf[fq][0], kb0, s);
        s  = mfma_h(qf[fq][1], kb1, s);
        xd = mfma_h(xq[fq], xb, xd);
        #pragma unroll
        for (int r=0;r<4;r++){
          float d2 = fmaxf(x2q[fq][r] + x2m - 2.f*xd[r], 0.f);
          S[fq][fm][r] = s[r]*0.125f + sig2*__expf(-d2*inv2l2);
        }
      }
    }

    // online softmax with deferred max (thr=4; P <= e^4, P^2 <= e^8 fits f16)
    #pragma unroll
    for (int fq=0; fq<2; fq++){
      f4 tm;
      #pragma unroll
      for (int r=0;r<4;r++)
        tm[r] = fmaxf(fmaxf(S[fq][0][r], S[fq][1][r]), fmaxf(S[fq][2][r], S[fq][3][r]));
      #pragma unroll
      for (int mask=1; mask<16; mask<<=1)
        #pragma unroll
        for (int r=0;r<4;r++) tm[r] = fmaxf(tm[r], __shfl_xor(tm[r], mask));
      int nd = 0;
      #pragma unroll
      for (int r=0;r<4;r++) nd |= (tm[r] > mrun[fq][r] + 4.f) ? 1 : 0;
      if (__any(nd)){
        f4 sc;
        #pragma unroll
        for (int r=0;r<4;r++){
          float mn = fmaxf(mrun[fq][r], tm[r]);
          sc[r] = __expf(mrun[fq][r] - mn);
          mrun[fq][r] = mn;
          lacc[fq][r] *= sc[r];
        }
        #pragma unroll
        for (int fd=0; fd<4; fd++)
          #pragma unroll
          for (int r=0;r<4;r++){
            ctx[fq][fd][r] *= sc[r];
            var[fq][fd][r] *= sc[r]*sc[r];
          }
      }
      #pragma unroll
      for (int fm=0; fm<4; fm++)
        #pragma unroll
        for (int r=0;r<4;r++){
          float p = __expf(S[fq][fm][r] - mrun[fq][r]);
          int qrow = wq + fq*16 + l4*4 + r;
          int m    = fm*16 + l15;
          int ck   = (m>>3) ^ (qrow & 7);
          sP[qrow*64 + ck*8 + (m&7)] = (_Float16)p;
        }
    }

    // PV: ctx += P @ V, var += P^2 @ Vv, l += P @ 1 (f16 MFMA)
    #pragma unroll
    for (int ks=0; ks<2; ks++){
      h8 pa[2], pa2[2];
      #pragma unroll
      for (int fq=0; fq<2; fq++){
        int qrow = wq + fq*16 + l15;
        int ck = (ks*4 + l4) ^ (qrow & 7);
        pa[fq] = *(const h8*)&sP[qrow*64 + ck*8];
        pa2[fq] = pa[fq]*pa[fq];
        lacc[fq] = mfma_h(pa[fq], ones, lacc[fq]);
      }
      #pragma unroll
      for (int fd=0; fd<4; fd++){
        int drow = fd*16 + l15;
        int ck = (ks*4 + l4) ^ (drow & 7);
        h8 vb  = *(const h8*)&sV[bi][drow*64 + ck*8];
        h8 vvb = *(const h8*)&sVv[bi][drow*64 + ck*8];
        #pragma unroll
        for (int fq=0; fq<2; fq++){
          ctx[fq][fd] = mfma_h(pa[fq],  vb,  ctx[fq][fd]);
          var[fq][fd] = mfma_h(pa2[fq], vvb, var[fq][fd]);
        }
      }
    }
    __syncthreads();
  }

  // epilogue: normalize; per row, group the 4 fd-stores so f16 writes form
  // full 128B lines (avoids partial-sector RMW at HBM).
  #pragma unroll
  for (int fq=0; fq<2; fq++)
    #pragma unroll
    for (int r=0;r<4;r++){
      int t = t0 + wq + fq*16 + l4*4 + r;
      float linv = 1.f / lacc[fq][r];
      size_t base = (size_t)t*D_MODEL + h*DK + l15;
      float c[4];
      #pragma unroll
      for (int fd=0; fd<4; fd++) c[fd] = ctx[fq][fd][r] * linv;
      #pragma unroll
      for (int fd=0; fd<4; fd++) ctx_out[base + fd*16]  = (_Float16)c[fd];
      #pragma unroll
      for (int fd=0; fd<4; fd++) ctx2_out[base + fd*16] = (_Float16)(c[fd]*c[fd]);
      #pragma unroll
      for (int fd=0; fd<4; fd++) var_out[base + fd*16]  = var[fq][fd][r] * linv * linv;
    }
}

// ---------------- host launch ----------------

extern "C" void kernel_launch(void* const* d_in, const int* in_sizes, int n_in,
                              void* d_out, int out_size, void* d_ws, size_t ws_size,
                              hipStream_t stream){
  (void)in_sizes; (void)n_in; (void)out_size; (void)ws_size;
  const float* H      = (const float*)d_in[0];
  const float* x_raw  = (const float*)d_in[1];
  const float* Wq_mu  = (const float*)d_in[2];
  const float* bq_mu  = (const float*)d_in[4];
  const float* Wk_mu  = (const float*)d_in[6];
  const float* bk_mu  = (const float*)d_in[8];
  const float* Wv_mu  = (const float*)d_in[10];
  const float* Wv_rho = (const float*)d_in[11];
  const float* bv_mu  = (const float*)d_in[12];
  const float* bv_rho = (const float*)d_in[13];
  const float* Wo_mu  = (const float*)d_in[14];
  const float* Wo_rho = (const float*)d_in[15];
  const float* bo_mu  = (const float*)d_in[16];
  const float* bo_rho = (const float*)d_in[17];
  const float* lsf    = (const float*)d_in[18];
  const float* lln    = (const float*)d_in[19];

  char* ws = (char*)d_ws;
  const size_t MB = 1024*1024;
  _Float16* Hh    = (_Float16*)(ws + 0*MB);     // 16MB
  _Float16* H2h   = (_Float16*)(ws + 16*MB);    // 16MB
  _Float16* Wcat  = (_Float16*)(ws + 32*MB);    // 8MB: [Wq|Wk|Wv|Wvs2] rows
  _Float16* Wocat = (_Float16*)(ws + 40*MB);    // 4MB: [Wo|Wos2] rows
  _Float16* Qh    = (_Float16*)(ws + 46*MB);    // 16MB
  _Float16* Kh    = (_Float16*)(ws + 62*MB);    // 16MB
  _Float16* Vt    = (_Float16*)(ws + 78*MB);    // 16MB, transposed [b][o][n]
  _Float16* Vvt   = (_Float16*)(ws + 94*MB);    // 16MB
  _Float16* ctxh  = (_Float16*)(ws + 110*MB);   // 16MB
  _Float16* ctx2h = (_Float16*)(ws + 126*MB);   // 16MB
  _Float16* xh    = (_Float16*)(ws + 142*MB);   // 256KB
  float*    x2    = (float*)(ws + 142*MB + 512*1024);  // 32KB

  float* out_mean = (float*)d_out;
  float* out_var  = out_mean + (size_t)TOK*D_MODEL;

  const int TD = TOK*D_MODEL;
  const int DD = D_MODEL*D_MODEL;

  // prep
  prep_H  <<<TD/1024, 256, 0, stream>>>(H, Hh, H2h, TD);
  cast_f16<<<DD/1024, 256, 0, stream>>>(Wq_mu, Wcat, DD);
  cast_f16<<<DD/1024, 256, 0, stream>>>(Wk_mu, Wcat + (size_t)DD, DD);
  cast_f16<<<DD/1024, 256, 0, stream>>>(Wv_mu, Wcat + 2*(size_t)DD, DD);
  sp2_f16 <<<DD/1024, 256, 0, stream>>>(Wv_rho, Wcat + 3*(size_t)DD, DD);
  cast_f16<<<DD/1024, 256, 0, stream>>>(Wo_mu, Wocat, DD);
  sp2_f16 <<<DD/1024, 256, 0, stream>>>(Wo_rho, Wocat + (size_t)DD, DD);
  prep_x  <<<TOK/256, 256, 0, stream>>>(x_raw, xh, x2, TOK);

  // fused projections: Q | K | V | Vv in one launch (grid 64 x 32)
  gemm_fused<0><<<2048, 256, 0, stream>>>(Hh, H2h, Wcat,
      bq_mu, bk_mu, bv_mu, bv_rho,
      Qh, Kh, Vt, Vvt, nullptr, nullptr);

  // attention (writes ctxh/ctx2h f16 and var_attn into out_var)
  attn_kernel<<<1024, 256, 0, stream>>>(Qh, Kh, Vt, Vvt, xh, x2, lsf, lln,
      ctxh, ctx2h, out_var);

  // fused output projections: out_mean | out_var (grid 64 x 16)
  gemm_fused<1><<<1024, 256, 0, stream>>>(ctxh, ctx2h, Wocat,
      bo_mu, bo_rho, nullptr, nullptr,
      nullptr, nullptr, nullptr, nullptr, out_mean, out_var);
}